// Round 4
// baseline (790.372 us; speedup 1.0000x reference)
//
#include <hip/hip_runtime.h>
#include <stdint.h>

typedef __attribute__((ext_vector_type(4))) float f32x4;
typedef __attribute__((ext_vector_type(16))) float f32x16;
typedef __attribute__((ext_vector_type(2))) float f32x2;
typedef __attribute__((ext_vector_type(8))) short s16x8;
typedef __attribute__((ext_vector_type(4))) unsigned short u16x4;

#define TOKENS 16384
#define IN_F 4096
#define OUT_F 4096
#define RNK 16
#define BM 256
#define BN 256
#define BK 64
#define NT (IN_F / BK)

static __device__ __forceinline__ unsigned short f32_to_bf16(float f) {
    uint32_t u = __builtin_bit_cast(uint32_t, f);
    uint32_t r = (u + 0x7FFFu + ((u >> 16) & 1u)) >> 16;
    return (unsigned short)r;
}

static __device__ __forceinline__ void direct_load16(const void* g, void* l) {
    __builtin_amdgcn_global_load_lds(
        (const __attribute__((address_space(1))) void*)(uintptr_t)g,
        (__attribute__((address_space(3))) void*)(uintptr_t)l,
        16, 0, 0);
}

static __device__ __forceinline__ f32x16 mfma32(s16x8 a, s16x8 b, f32x16 c) {
    return __builtin_amdgcn_mfma_f32_32x32x16_bf16(a, b, c, 0, 0, 0);
}

#define RAW_BARRIER() asm volatile("s_barrier" ::: "memory")
#define WAIT_VM0_LGKM0() asm volatile("s_waitcnt vmcnt(0) lgkmcnt(0)" ::: "memory")

// ---------------- Kernel A: per-row absmax int8 quant-dequant -> bf16, + lora_b transpose ----------------
__global__ __launch_bounds__(256) void qd_weight_kernel(const float* __restrict__ w,
                                                        const float* __restrict__ lb,
                                                        unsigned short* __restrict__ wbf,
                                                        unsigned short* __restrict__ lbt) {
    const int row = blockIdx.x;
    const int tid = threadIdx.x;
    const float* wr = w + (size_t)row * IN_F;
    f32x4 v[4];
#pragma unroll
    for (int p = 0; p < 4; ++p)
        v[p] = *(const f32x4*)(wr + (size_t)(tid + p * 256) * 4);
    float m = 0.f;
#pragma unroll
    for (int p = 0; p < 4; ++p)
#pragma unroll
        for (int e = 0; e < 4; ++e)
            m = fmaxf(m, fabsf(v[p][e]));
#pragma unroll
    for (int off = 1; off < 64; off <<= 1)
        m = fmaxf(m, __shfl_xor(m, off, 64));
    __shared__ float red[4];
    if ((tid & 63) == 0) red[tid >> 6] = m;
    __syncthreads();
    m = fmaxf(fmaxf(red[0], red[1]), fmaxf(red[2], red[3]));
    const float scale = m * (1.0f / 127.0f);
    const float denom = scale + 1e-8f;
#pragma unroll
    for (int p = 0; p < 4; ++p) {
        u16x4 q4;
#pragma unroll
        for (int e = 0; e < 4; ++e) {
            float q = rintf(v[p][e] / denom);  // RNE, matches jnp.round
            q = fminf(fmaxf(q, -128.f), 127.f);
            q4[e] = f32_to_bf16(q * scale);
        }
        *(u16x4*)(wbf + (size_t)row * IN_F + (size_t)(tid + p * 256) * 4) = q4;
    }
    // lbt[col][r] = bf16(lb[r][col]) ; this block handles col = row
    if (tid < RNK)
        lbt[(size_t)row * RNK + tid] = f32_to_bf16(lb[(size_t)tid * OUT_F + row]);
}

// ------------- Kernel B: x f32 -> bf16 conversion fused with t = bf16(2*(x @ lora_a)) -------------
__global__ __launch_bounds__(256) void conv_lora_kernel(const float* __restrict__ x,
                                                        const float* __restrict__ la,
                                                        unsigned short* __restrict__ xbf,
                                                        unsigned short* __restrict__ tbf) {
    const int tid = threadIdx.x;
    const int lane = tid & 63;
    const int wid = tid >> 6;
    const int tok0 = blockIdx.x * 16 + wid * 4;
    float acc[4][16];
#pragma unroll
    for (int ti = 0; ti < 4; ++ti)
#pragma unroll
        for (int r = 0; r < 16; ++r) acc[ti][r] = 0.f;

    for (int j = 0; j < 32; ++j) {
        const int k = j * 128 + lane * 2;
        const float* lap = la + (size_t)k * RNK;
        f32x4 A[4], B[4];
#pragma unroll
        for (int h = 0; h < 4; ++h) A[h] = *(const f32x4*)(lap + h * 4);
#pragma unroll
        for (int h = 0; h < 4; ++h) B[h] = *(const f32x4*)(lap + RNK + h * 4);
#pragma unroll
        for (int ti = 0; ti < 4; ++ti) {
            const int t = tok0 + ti;
            f32x2 xv = *(const f32x2*)(x + (size_t)t * IN_F + k);
            const float xa = xv[0], xb = xv[1];
            uint32_t pack = (uint32_t)f32_to_bf16(xa) | ((uint32_t)f32_to_bf16(xb) << 16);
            *(uint32_t*)(xbf + (size_t)t * IN_F + k) = pack;
#pragma unroll
            for (int h = 0; h < 4; ++h)
#pragma unroll
                for (int e = 0; e < 4; ++e)
                    acc[ti][h * 4 + e] += xa * A[h][e] + xb * B[h][e];
        }
    }
#pragma unroll
    for (int ti = 0; ti < 4; ++ti)
#pragma unroll
        for (int r = 0; r < 16; ++r) {
            float s = acc[ti][r];
#pragma unroll
            for (int off = 1; off < 64; off <<= 1)
                s += __shfl_xor(s, off, 64);
            acc[ti][r] = s;
        }
    if (lane == 0) {
#pragma unroll
        for (int ti = 0; ti < 4; ++ti)
#pragma unroll
            for (int r = 0; r < 16; ++r)
                tbf[(size_t)(tok0 + ti) * RNK + r] = f32_to_bf16(2.0f * acc[ti][r]);
    }
}

// ------------- Kernel C: 256x256 pipelined 32x32x16 MFMA GEMM + MFMA LoRA epilogue -------------
// 512 threads = 8 waves (2M x 4N), per-wave 128x64 out = 4x2 tiles of 32x32.
// BK=64 = 4 k-slices of 16. Fragments software-pipelined one slice ahead; NO intra-tile
// barriers (LDS pipe overlaps matrix pipe); one vmcnt(0)+lgkmcnt(0)+barrier per K-tile.
__global__ __launch_bounds__(512, 2) void gemm32_kernel(const unsigned short* __restrict__ xbf,
                                                        const unsigned short* __restrict__ wbf,
                                                        const unsigned short* __restrict__ tbf,
                                                        const unsigned short* __restrict__ lbt,
                                                        float* __restrict__ out) {
    __shared__ char lds[131072];  // A0 | A1 | B0 | B1, 32KB each

    const int bid = blockIdx.x;
    // bijective XCD swizzle (1024 % 8 == 0): each XCD owns 2 B-panels (4MB = its L2)
    const int swz = (bid & 7) * 128 + (bid >> 3);
    const int tm = swz & 63, tn = swz >> 6;
    const int brow = tm * BM, bcol = tn * BN;

    const int tid = threadIdx.x;
    const int lane = tid & 63;
    const int wid = tid >> 6;
    const int wm = wid >> 2, wn = wid & 3;
    const int l31 = lane & 31;
    const int lkh = lane >> 5;  // k-half selector for 32x32 operands

    // ---- staging source (pre-swizzled global col so linear LDS dest == swizzled store) ----
    const int s_r = tid >> 3;                                    // row within 64-row issue block
    const int scb = ((tid & 7) * 16) ^ (((tid >> 3) & 7) << 4);  // swizzled col-byte (0..127)
    const unsigned short* gA = xbf + (size_t)(brow + s_r) * IN_F + (scb >> 1);
    const unsigned short* gB = wbf + (size_t)(bcol + s_r) * IN_F + (scb >> 1);

    // ---- fragment addressing: A row = wm*128 + mt*32 + l31, B col-row = wn*64 + nt*32 + l31 ----
    const int aBase = (wm * 128 + l31) * 128;  // + mt*4096 + koff[ks]
    const int bBase = (wn * 64 + l31) * 128;   // + nt*4096 + koff[ks]
    int koff[4];
#pragma unroll
    for (int ks = 0; ks < 4; ++ks)
        koff[ks] = ((ks * 32) + lkh * 16) ^ ((lane & 7) << 4);

    f32x16 acc[4][2];
#pragma unroll
    for (int mt = 0; mt < 4; ++mt)
#pragma unroll
        for (int nt = 0; nt < 2; ++nt)
#pragma unroll
            for (int q = 0; q < 16; ++q) acc[mt][nt][q] = 0.f;

    // ---- prologue: stage tile 0 into buffer 0 ----
#pragma unroll
    for (int i = 0; i < 4; ++i)
        direct_load16(gA + (size_t)(i * 64) * IN_F, lds + i * 8192 + tid * 16);
#pragma unroll
    for (int i = 0; i < 4; ++i)
        direct_load16(gB + (size_t)(i * 64) * IN_F, lds + 65536 + i * 8192 + tid * 16);
    WAIT_VM0_LGKM0();
    __syncthreads();

    s16x8 af[2][4], bf[2][2];
    // preload slice 0 of tile 0
#pragma unroll
    for (int mt = 0; mt < 4; ++mt)
        af[0][mt] = *(const s16x8*)(lds + aBase + mt * 4096 + koff[0]);
#pragma unroll
    for (int nt = 0; nt < 2; ++nt)
        bf[0][nt] = *(const s16x8*)(lds + 65536 + bBase + nt * 4096 + koff[0]);

    for (int t = 0; t < NT; ++t) {
        const int sel = t & 1;
        const char* A = lds + sel * 32768;
        const char* B = lds + 65536 + sel * 32768;
        char* An = lds + (sel ^ 1) * 32768;
        char* Bn = lds + 65536 + (sel ^ 1) * 32768;
        const int k1 = (t + 1) * BK;
        const bool pf = (t + 1 < NT);

#pragma unroll
        for (int ks = 0; ks < 4; ++ks) {
            const int cur = ks & 1, nxt = cur ^ 1;
            // stage next tile: 4 A-loads at ks0, 4 B-loads at ks1
            if (ks == 0 && pf) {
#pragma unroll
                for (int i = 0; i < 4; ++i)
                    direct_load16(gA + (size_t)(i * 64) * IN_F + k1, An + i * 8192 + tid * 16);
            }
            if (ks == 1 && pf) {
#pragma unroll
                for (int i = 0; i < 4; ++i)
                    direct_load16(gB + (size_t)(i * 64) * IN_F + k1, Bn + i * 8192 + tid * 16);
            }
            if (ks < 3) {
                // read slice ks+1 fragments (overlaps this slice's MFMAs)
#pragma unroll
                for (int mt = 0; mt < 4; ++mt)
                    af[nxt][mt] = *(const s16x8*)(A + aBase + mt * 4096 + koff[ks + 1]);
#pragma unroll
                for (int nt = 0; nt < 2; ++nt)
                    bf[nxt][nt] = *(const s16x8*)(B + bBase + nt * 4096 + koff[ks + 1]);
            } else if (pf) {
                // tile boundary: own loads drained + own ds_reads drained BEFORE barrier
                // (other waves' t+2 stage loads may overwrite this buffer after the barrier)
                WAIT_VM0_LGKM0();
                RAW_BARRIER();
                // preload slice 0 of tile t+1 (overlaps slice-3 MFMAs below)
#pragma unroll
                for (int mt = 0; mt < 4; ++mt)
                    af[nxt][mt] = *(const s16x8*)(An + aBase + mt * 4096 + koff[0]);
#pragma unroll
                for (int nt = 0; nt < 2; ++nt)
                    bf[nxt][nt] = *(const s16x8*)(Bn + bBase + nt * 4096 + koff[0]);
            }
            __builtin_amdgcn_s_setprio(1);
#pragma unroll
            for (int mt = 0; mt < 4; ++mt)
#pragma unroll
                for (int nt = 0; nt < 2; ++nt)
                    acc[mt][nt] = mfma32(af[cur][mt], bf[cur][nt], acc[mt][nt]);
            __builtin_amdgcn_s_setprio(0);
        }
    }

    // ---- LoRA epilogue: acc[mt][nt] += t_tile(32x16) @ lbt_tile(32x16)^T, one K=16 MFMA each ----
    __syncthreads();  // drains lgkm + all waves done with main loop
    unsigned short* tls = (unsigned short*)lds;           // [256][16]
    unsigned short* lls = (unsigned short*)(lds + 8192);  // [256][16]
    {
        const int row = tid >> 1, h = tid & 1;
        *(s16x8*)(tls + row * 16 + h * 8) = *(const s16x8*)(tbf + (size_t)(brow + row) * RNK + h * 8);
        *(s16x8*)(lls + row * 16 + h * 8) = *(const s16x8*)(lbt + (size_t)(bcol + row) * RNK + h * 8);
    }
    __syncthreads();
#pragma unroll
    for (int mt = 0; mt < 4; ++mt) {
        s16x8 at = *(const s16x8*)(tls + (wm * 128 + mt * 32 + l31) * 16 + lkh * 8);
#pragma unroll
        for (int nt = 0; nt < 2; ++nt) {
            s16x8 bl = *(const s16x8*)(lls + (wn * 64 + nt * 32 + l31) * 16 + lkh * 8);
            acc[mt][nt] = mfma32(at, bl, acc[mt][nt]);
        }
    }

    // ---- store: 32x32 C/D layout col=lane&31, row=(reg&3)+8*(reg>>2)+4*(lane>>5) (verified m74/m101) ----
    const int c0 = bcol + wn * 64 + l31;
#pragma unroll
    for (int mt = 0; mt < 4; ++mt)
#pragma unroll
        for (int q = 0; q < 16; ++q) {
            const int row = brow + wm * 128 + mt * 32 + (q & 3) + 8 * (q >> 2) + 4 * lkh;
            float* orow = out + (size_t)row * OUT_F;
#pragma unroll
            for (int nt = 0; nt < 2; ++nt)
                orow[c0 + nt * 32] = acc[mt][nt][q];
        }
}

extern "C" void kernel_launch(void* const* d_in, const int* in_sizes, int n_in,
                              void* d_out, int out_size, void* d_ws, size_t ws_size,
                              hipStream_t stream) {
    const float* x  = (const float*)d_in[0];
    const float* w  = (const float*)d_in[1];
    const float* la = (const float*)d_in[2];
    const float* lb = (const float*)d_in[3];
    float* out = (float*)d_out;

    char* ws = (char*)d_ws;
    unsigned short* xbf = (unsigned short*)ws;                                    // 128 MiB
    unsigned short* wbf = (unsigned short*)(ws + (size_t)TOKENS * IN_F * 2);      // 32 MiB
    unsigned short* tbf = (unsigned short*)(ws + (size_t)TOKENS * IN_F * 2 + (size_t)OUT_F * IN_F * 2);           // 512 KiB
    unsigned short* lbt = (unsigned short*)(ws + (size_t)TOKENS * IN_F * 2 + (size_t)OUT_F * IN_F * 2
                                               + (size_t)TOKENS * RNK * 2);       // 128 KiB

    qd_weight_kernel<<<OUT_F, 256, 0, stream>>>(w, lb, wbf, lbt);
    conv_lora_kernel<<<TOKENS / 16, 256, 0, stream>>>(x, la, xbf, tbf);
    gemm32_kernel<<<(TOKENS / BM) * (OUT_F / BN), 512, 0, stream>>>(xbf, wbf, tbf, lbt, out);
}

// Round 5
// 745.272 us; speedup vs baseline: 1.0605x; 1.0605x over previous
//
#include <hip/hip_runtime.h>
#include <stdint.h>

typedef __attribute__((ext_vector_type(4))) float f32x4;
typedef __attribute__((ext_vector_type(2))) float f32x2;
typedef __attribute__((ext_vector_type(8))) short s16x8;
typedef __attribute__((ext_vector_type(4))) unsigned short u16x4;

#define TOKENS 16384
#define IN_F 4096
#define OUT_F 4096
#define RNK 16
#define BM 256
#define BN 256
#define BK 64
#define NT (IN_F / BK)

static __device__ __forceinline__ unsigned short f32_to_bf16(float f) {
    uint32_t u = __builtin_bit_cast(uint32_t, f);
    uint32_t r = (u + 0x7FFFu + ((u >> 16) & 1u)) >> 16;
    return (unsigned short)r;
}

static __device__ __forceinline__ void direct_load16(const void* g, void* l) {
    __builtin_amdgcn_global_load_lds(
        (const __attribute__((address_space(1))) void*)(uintptr_t)g,
        (__attribute__((address_space(3))) void*)(uintptr_t)l,
        16, 0, 0);
}

static __device__ __forceinline__ f32x4 mfma16(s16x8 a, s16x8 b, f32x4 c) {
    return __builtin_amdgcn_mfma_f32_16x16x32_bf16(a, b, c, 0, 0, 0);
}

#define BAR() asm volatile("s_barrier" ::: "memory")
#define VM(n) asm volatile("s_waitcnt vmcnt(" #n ")" ::: "memory")
#define LGKM(n)                                          \
    do {                                                 \
        asm volatile("s_waitcnt lgkmcnt(" #n ")" ::: "memory"); \
        __builtin_amdgcn_sched_barrier(0);               \
    } while (0)

// ---------------- Kernel A: per-row absmax int8 quant-dequant -> bf16, + lora_b transpose ----------------
__global__ __launch_bounds__(256) void qd_weight_kernel(const float* __restrict__ w,
                                                        const float* __restrict__ lb,
                                                        unsigned short* __restrict__ wbf,
                                                        unsigned short* __restrict__ lbt) {
    const int row = blockIdx.x;
    const int tid = threadIdx.x;
    const float* wr = w + (size_t)row * IN_F;
    f32x4 v[4];
#pragma unroll
    for (int p = 0; p < 4; ++p)
        v[p] = *(const f32x4*)(wr + (size_t)(tid + p * 256) * 4);
    float m = 0.f;
#pragma unroll
    for (int p = 0; p < 4; ++p)
#pragma unroll
        for (int e = 0; e < 4; ++e)
            m = fmaxf(m, fabsf(v[p][e]));
#pragma unroll
    for (int off = 1; off < 64; off <<= 1)
        m = fmaxf(m, __shfl_xor(m, off, 64));
    __shared__ float red[4];
    if ((tid & 63) == 0) red[tid >> 6] = m;
    __syncthreads();
    m = fmaxf(fmaxf(red[0], red[1]), fmaxf(red[2], red[3]));
    const float scale = m * (1.0f / 127.0f);
    const float denom = scale + 1e-8f;
#pragma unroll
    for (int p = 0; p < 4; ++p) {
        u16x4 q4;
#pragma unroll
        for (int e = 0; e < 4; ++e) {
            float q = rintf(v[p][e] / denom);  // RNE, matches jnp.round
            q = fminf(fmaxf(q, -128.f), 127.f);
            q4[e] = f32_to_bf16(q * scale);
        }
        *(u16x4*)(wbf + (size_t)row * IN_F + (size_t)(tid + p * 256) * 4) = q4;
    }
    if (tid < RNK)
        lbt[(size_t)row * RNK + tid] = f32_to_bf16(lb[(size_t)tid * OUT_F + row]);
}

// ------------- Kernel B: x f32 -> bf16 conversion fused with t = bf16(2*(x @ lora_a)) -------------
__global__ __launch_bounds__(256) void conv_lora_kernel(const float* __restrict__ x,
                                                        const float* __restrict__ la,
                                                        unsigned short* __restrict__ xbf,
                                                        unsigned short* __restrict__ tbf) {
    const int tid = threadIdx.x;
    const int lane = tid & 63;
    const int wid = tid >> 6;
    const int tok0 = blockIdx.x * 16 + wid * 4;
    float acc[4][16];
#pragma unroll
    for (int ti = 0; ti < 4; ++ti)
#pragma unroll
        for (int r = 0; r < 16; ++r) acc[ti][r] = 0.f;

    for (int j = 0; j < 32; ++j) {
        const int k = j * 128 + lane * 2;
        const float* lap = la + (size_t)k * RNK;
        f32x4 A[4], B[4];
#pragma unroll
        for (int h = 0; h < 4; ++h) A[h] = *(const f32x4*)(lap + h * 4);
#pragma unroll
        for (int h = 0; h < 4; ++h) B[h] = *(const f32x4*)(lap + RNK + h * 4);
#pragma unroll
        for (int ti = 0; ti < 4; ++ti) {
            const int t = tok0 + ti;
            f32x2 xv = *(const f32x2*)(x + (size_t)t * IN_F + k);
            const float xa = xv[0], xb = xv[1];
            uint32_t pack = (uint32_t)f32_to_bf16(xa) | ((uint32_t)f32_to_bf16(xb) << 16);
            *(uint32_t*)(xbf + (size_t)t * IN_F + k) = pack;
#pragma unroll
            for (int h = 0; h < 4; ++h)
#pragma unroll
                for (int e = 0; e < 4; ++e)
                    acc[ti][h * 4 + e] += xa * A[h][e] + xb * B[h][e];
        }
    }
#pragma unroll
    for (int ti = 0; ti < 4; ++ti)
#pragma unroll
        for (int r = 0; r < 16; ++r) {
            float s = acc[ti][r];
#pragma unroll
            for (int off = 1; off < 64; off <<= 1)
                s += __shfl_xor(s, off, 64);
            acc[ti][r] = s;
        }
    if (lane == 0) {
#pragma unroll
        for (int ti = 0; ti < 4; ++ti)
#pragma unroll
            for (int r = 0; r < 16; ++r)
                tbf[(size_t)(tok0 + ti) * RNK + r] = f32_to_bf16(2.0f * acc[ti][r]);
    }
}

// ------------- Kernel C: 256x256 4-phase/tile bf16 MFMA GEMM, counted vmcnt/lgkm gates -------------
// 512 threads = 8 waves (2M x 4N), 16x16x32 MFMA, BK=64, dbuf 128KB LDS, XOR-swizzle (R2, 0-conflict).
// Per tile: ph0{burst-stage t+1 | read bL+bH | Q00}, ph1{read aH | Q01}, ph2{Q11}, ph3{read aL(t+1) | Q10}.
// One barrier per phase. vmcnt gates: 8@ph0, 6@ph2, 2@ph3 (never 0 in steady state).
__global__ __launch_bounds__(512, 2) void gemm4p_kernel(const unsigned short* __restrict__ xbf,
                                                        const unsigned short* __restrict__ wbf,
                                                        const unsigned short* __restrict__ tbf,
                                                        const unsigned short* __restrict__ lbt,
                                                        float* __restrict__ out) {
    __shared__ char lds[131072];  // A0 | A1 | B0 | B1, 32KB each

    const int bid = blockIdx.x;
    const int swz = (bid & 7) * 128 + (bid >> 3);  // bijective XCD swizzle (1024 % 8 == 0)
    const int tm = swz & 63, tn = swz >> 6;
    const int brow = tm * BM, bcol = tn * BN;

    const int tid = threadIdx.x;
    const int lane = tid & 63;
    const int wid = tid >> 6;
    const int wm = wid >> 2, wn = wid & 3;
    const int lrow = lane & 15;
    const int lko = lane >> 4;

    // ---- staging source (pre-swizzled global col so linear LDS dest == swizzled store) ----
    const int s_r = tid >> 3;                                    // 0..63
    const int scb = ((tid & 7) * 16) ^ (((tid >> 3) & 7) << 4);  // swizzled col-byte
    const unsigned short* gA = xbf + (size_t)(brow + s_r) * IN_F + (scb >> 1);
    // B half-tiles: lower/upper 32 rows of each 64-row chunk. rB = (s&31) + (s>>5)*64; (rB&7)==(s&7).
    const int rB = (s_r & 31) + (s_r >> 5) * 64;
    const unsigned short* gB = wbf + (size_t)(bcol + rB) * IN_F + (scb >> 1);
    const int dB = rB * 128 + (tid & 7) * 16;  // LDS byte dest for B-lo j=0

    // ---- fragment ds_read addressing (swizzled; R2 pattern, verified 0-conflict) ----
    const int aBase = (wm * 128 + lrow) * 128;
    const int bBase = (wn * 64 + lrow) * 128;
    const int koff[2] = {(lko * 16) ^ ((lrow & 7) << 4),
                         ((lko * 16) | 64) ^ ((lrow & 7) << 4)};

    f32x4 acc[8][4];
#pragma unroll
    for (int mf = 0; mf < 8; ++mf)
#pragma unroll
        for (int nf = 0; nf < 4; ++nf)
#pragma unroll
            for (int q = 0; q < 4; ++q) acc[mf][nf][q] = 0.f;

// burst: stage tile (k-offset kk) into Adst/Bdst. Issue order Alo(2), Blo(2), Bhi(2), Ahi(2).
#define BURST(kk, Adst, Bdst)                                                            \
    do {                                                                                 \
        direct_load16(gA + (size_t)0 * IN_F + (kk), (Adst) + tid * 16);                  \
        direct_load16(gA + (size_t)128 * IN_F + (kk), (Adst) + 16384 + tid * 16);        \
        direct_load16(gB + (size_t)0 * IN_F + (kk), (Bdst) + dB);                        \
        direct_load16(gB + (size_t)128 * IN_F + (kk), (Bdst) + 16384 + dB);              \
        direct_load16(gB + (size_t)32 * IN_F + (kk), (Bdst) + 4096 + dB);                \
        direct_load16(gB + (size_t)160 * IN_F + (kk), (Bdst) + 20480 + dB);              \
        direct_load16(gA + (size_t)64 * IN_F + (kk), (Adst) + 8192 + tid * 16);          \
        direct_load16(gA + (size_t)192 * IN_F + (kk), (Adst) + 24576 + tid * 16);        \
    } while (0)

    // ---- prologue: stage tile 0 -> buf0, drain, preload aL(0) ----
    BURST(0, lds, lds + 65536);
    VM(0);
    __syncthreads();

    s16x8 aL[4][2], aH[4][2], bL[2][2], bH[2][2];
#pragma unroll
    for (int mf = 0; mf < 4; ++mf) {
        aL[mf][0] = *(const s16x8*)(lds + aBase + mf * 2048 + koff[0]);
        aL[mf][1] = *(const s16x8*)(lds + aBase + mf * 2048 + koff[1]);
    }

    for (int t = 0; t < NT; ++t) {
        const int sel = t & 1;
        const char* A = lds + sel * 32768;
        const char* B = lds + 65536 + sel * 32768;
        char* An = (char*)lds + (sel ^ 1) * 32768;
        char* Bn = (char*)lds + 65536 + (sel ^ 1) * 32768;
        const bool pf = (t + 1 < NT);

        // ===== ph0: burst-stage tile t+1 | read bL,bH(t) | MFMA Q00 (aL x bL) =====
        if (pf) BURST((t + 1) * BK, An, Bn);
#pragma unroll
        for (int nf = 0; nf < 2; ++nf) {
            bL[nf][0] = *(const s16x8*)(B + bBase + nf * 2048 + koff[0]);
            bL[nf][1] = *(const s16x8*)(B + bBase + nf * 2048 + koff[1]);
        }
#pragma unroll
        for (int nf = 0; nf < 2; ++nf) {
            bH[nf][0] = *(const s16x8*)(B + bBase + (2 + nf) * 2048 + koff[0]);
            bH[nf][1] = *(const s16x8*)(B + bBase + (2 + nf) * 2048 + koff[1]);
        }
        LGKM(4);  // aL(8 prev) + bL(4) done; bH(4) outstanding
        __builtin_amdgcn_s_setprio(1);
#pragma unroll
        for (int mf = 0; mf < 4; ++mf)
#pragma unroll
            for (int nf = 0; nf < 2; ++nf) {
                acc[mf][nf] = mfma16(aL[mf][0], bL[nf][0], acc[mf][nf]);
                acc[mf][nf] = mfma16(aL[mf][1], bL[nf][1], acc[mf][nf]);
            }
        __builtin_amdgcn_s_setprio(0);
        if (pf) { VM(8); } else { VM(0); }  // Ahi(t) landed (for ph1's aH reads)
        BAR();

        // ===== ph1: read aH(t) | MFMA Q01 (aL x bH) =====
#pragma unroll
        for (int mf = 0; mf < 4; ++mf) {
            aH[mf][0] = *(const s16x8*)(A + aBase + (4 + mf) * 2048 + koff[0]);
            aH[mf][1] = *(const s16x8*)(A + aBase + (4 + mf) * 2048 + koff[1]);
        }
        LGKM(8);  // bH done; aH outstanding
        __builtin_amdgcn_s_setprio(1);
#pragma unroll
        for (int mf = 0; mf < 4; ++mf)
#pragma unroll
            for (int nf = 0; nf < 2; ++nf) {
                acc[mf][2 + nf] = mfma16(aL[mf][0], bH[nf][0], acc[mf][2 + nf]);
                acc[mf][2 + nf] = mfma16(aL[mf][1], bH[nf][1], acc[mf][2 + nf]);
            }
        __builtin_amdgcn_s_setprio(0);
        BAR();

        // ===== ph2: MFMA Q11 (aH x bH) =====
        LGKM(0);  // aH done
        __builtin_amdgcn_s_setprio(1);
#pragma unroll
        for (int mf = 0; mf < 4; ++mf)
#pragma unroll
            for (int nf = 0; nf < 2; ++nf) {
                acc[4 + mf][2 + nf] = mfma16(aH[mf][0], bH[nf][0], acc[4 + mf][2 + nf]);
                acc[4 + mf][2 + nf] = mfma16(aH[mf][1], bH[nf][1], acc[4 + mf][2 + nf]);
            }
        __builtin_amdgcn_s_setprio(0);
        if (pf) { VM(6); }  // Alo(t+1) landed (for ph3's aL reads)
        BAR();

        // ===== ph3: read aL(t+1) | MFMA Q10 (aH x bL) =====
        if (pf) {
#pragma unroll
            for (int mf = 0; mf < 4; ++mf) {
                aL[mf][0] = *(const s16x8*)(An + aBase + mf * 2048 + koff[0]);
                aL[mf][1] = *(const s16x8*)(An + aBase + mf * 2048 + koff[1]);
            }
        }
        __builtin_amdgcn_s_setprio(1);
#pragma unroll
        for (int mf = 0; mf < 4; ++mf)
#pragma unroll
            for (int nf = 0; nf < 2; ++nf) {
                acc[4 + mf][nf] = mfma16(aH[mf][0], bL[nf][0], acc[4 + mf][nf]);
                acc[4 + mf][nf] = mfma16(aH[mf][1], bL[nf][1], acc[4 + mf][nf]);
            }
        __builtin_amdgcn_s_setprio(0);
        if (pf) { VM(2); }  // Blo,Bhi(t+1) landed (for next ph0's b reads)
        BAR();
    }
#undef BURST

    // ---- LoRA epilogue via MFMA: acc += t_tile(256x16) @ lbt_tile(256x16)^T (K=32, k>=16 zero) ----
    __syncthreads();
    unsigned short* tls = (unsigned short*)lds;           // [256][16]
    unsigned short* lls = (unsigned short*)(lds + 8192);  // [256][16]
    {
        const int row = tid >> 1, h = tid & 1;
        *(s16x8*)(tls + row * 16 + h * 8) = *(const s16x8*)(tbf + (size_t)(brow + row) * RNK + h * 8);
        *(s16x8*)(lls + row * 16 + h * 8) = *(const s16x8*)(lbt + (size_t)(bcol + row) * RNK + h * 8);
    }
    __syncthreads();
    {
        s16x8 z;
#pragma unroll
        for (int e = 0; e < 8; ++e) z[e] = 0;
        s16x8 at8[8], bl8[4];
#pragma unroll
        for (int mf = 0; mf < 8; ++mf) {
            const int row = wm * 128 + mf * 16 + lrow;
            at8[mf] = (lko < 2) ? *(const s16x8*)(tls + row * 16 + lko * 8) : z;
        }
#pragma unroll
        for (int nf = 0; nf < 4; ++nf) {
            const int row = wn * 64 + nf * 16 + lrow;
            bl8[nf] = (lko < 2) ? *(const s16x8*)(lls + row * 16 + lko * 8) : z;
        }
#pragma unroll
        for (int mf = 0; mf < 8; ++mf)
#pragma unroll
            for (int nf = 0; nf < 4; ++nf)
                acc[mf][nf] = mfma16(at8[mf], bl8[nf], acc[mf][nf]);
    }

    // ---- store: C/D layout col=lane&15, row=(lane>>4)*4+q (verified) ----
    const int c0 = bcol + wn * 64 + lrow;
    const int r0base = brow + wm * 128 + lko * 4;
#pragma unroll
    for (int mf = 0; mf < 8; ++mf)
#pragma unroll
        for (int q = 0; q < 4; ++q) {
            float* orow = out + (size_t)(r0base + mf * 16 + q) * OUT_F;
#pragma unroll
            for (int nf = 0; nf < 4; ++nf)
                orow[c0 + nf * 16] = acc[mf][nf][q];
        }
}

extern "C" void kernel_launch(void* const* d_in, const int* in_sizes, int n_in,
                              void* d_out, int out_size, void* d_ws, size_t ws_size,
                              hipStream_t stream) {
    const float* x  = (const float*)d_in[0];
    const float* w  = (const float*)d_in[1];
    const float* la = (const float*)d_in[2];
    const float* lb = (const float*)d_in[3];
    float* out = (float*)d_out;

    char* ws = (char*)d_ws;
    unsigned short* xbf = (unsigned short*)ws;                                    // 128 MiB
    unsigned short* wbf = (unsigned short*)(ws + (size_t)TOKENS * IN_F * 2);      // 32 MiB
    unsigned short* tbf = (unsigned short*)(ws + (size_t)TOKENS * IN_F * 2 + (size_t)OUT_F * IN_F * 2);           // 512 KiB
    unsigned short* lbt = (unsigned short*)(ws + (size_t)TOKENS * IN_F * 2 + (size_t)OUT_F * IN_F * 2
                                               + (size_t)TOKENS * RNK * 2);       // 128 KiB

    qd_weight_kernel<<<OUT_F, 256, 0, stream>>>(w, lb, wbf, lbt);
    conv_lora_kernel<<<TOKENS / 16, 256, 0, stream>>>(x, la, xbf, tbf);
    gemm4p_kernel<<<(TOKENS / BM) * (OUT_F / BN), 512, 0, stream>>>(xbf, wbf, tbf, lbt, out);
}

// Round 6
// 711.339 us; speedup vs baseline: 1.1111x; 1.0477x over previous
//
#include <hip/hip_runtime.h>
#include <stdint.h>

typedef __attribute__((ext_vector_type(4))) float f32x4;
typedef __attribute__((ext_vector_type(2))) float f32x2;
typedef __attribute__((ext_vector_type(8))) short s16x8;
typedef __attribute__((ext_vector_type(4))) unsigned short u16x4;

#define TOKENS 16384
#define IN_F 4096
#define OUT_F 4096
#define RNK 16
#define BM 256
#define BN 256
#define BK 64
#define NT (IN_F / BK)

static __device__ __forceinline__ unsigned short f32_to_bf16(float f) {
    uint32_t u = __builtin_bit_cast(uint32_t, f);
    uint32_t r = (u + 0x7FFFu + ((u >> 16) & 1u)) >> 16;
    return (unsigned short)r;
}

static __device__ __forceinline__ void direct_load16(const void* g, void* l) {
    __builtin_amdgcn_global_load_lds(
        (const __attribute__((address_space(1))) void*)(uintptr_t)g,
        (__attribute__((address_space(3))) void*)(uintptr_t)l,
        16, 0, 0);
}

static __device__ __forceinline__ f32x4 mfma16(s16x8 a, s16x8 b, f32x4 c) {
    return __builtin_amdgcn_mfma_f32_16x16x32_bf16(a, b, c, 0, 0, 0);
}

#define BAR() asm volatile("s_barrier" ::: "memory")
#define VM(n) asm volatile("s_waitcnt vmcnt(" #n ")" ::: "memory")
#define LGKM0()                                                  \
    do {                                                         \
        asm volatile("s_waitcnt lgkmcnt(0)" ::: "memory");       \
        __builtin_amdgcn_sched_barrier(0);                       \
    } while (0)
#define LGKM8() asm volatile("s_waitcnt lgkmcnt(8)" ::: "memory")

// ---------------- Kernel A: per-row absmax int8 quant-dequant -> bf16, + lora_b transpose ----------------
__global__ __launch_bounds__(256) void qd_weight_kernel(const float* __restrict__ w,
                                                        const float* __restrict__ lb,
                                                        unsigned short* __restrict__ wbf,
                                                        unsigned short* __restrict__ lbt) {
    const int row = blockIdx.x;
    const int tid = threadIdx.x;
    const float* wr = w + (size_t)row * IN_F;
    f32x4 v[4];
#pragma unroll
    for (int p = 0; p < 4; ++p)
        v[p] = *(const f32x4*)(wr + (size_t)(tid + p * 256) * 4);
    float m = 0.f;
#pragma unroll
    for (int p = 0; p < 4; ++p)
#pragma unroll
        for (int e = 0; e < 4; ++e)
            m = fmaxf(m, fabsf(v[p][e]));
#pragma unroll
    for (int off = 1; off < 64; off <<= 1)
        m = fmaxf(m, __shfl_xor(m, off, 64));
    __shared__ float red[4];
    if ((tid & 63) == 0) red[tid >> 6] = m;
    __syncthreads();
    m = fmaxf(fmaxf(red[0], red[1]), fmaxf(red[2], red[3]));
    const float scale = m * (1.0f / 127.0f);
    const float denom = scale + 1e-8f;
#pragma unroll
    for (int p = 0; p < 4; ++p) {
        u16x4 q4;
#pragma unroll
        for (int e = 0; e < 4; ++e) {
            float q = rintf(v[p][e] / denom);  // RNE, matches jnp.round
            q = fminf(fmaxf(q, -128.f), 127.f);
            q4[e] = f32_to_bf16(q * scale);
        }
        *(u16x4*)(wbf + (size_t)row * IN_F + (size_t)(tid + p * 256) * 4) = q4;
    }
    if (tid < RNK)
        lbt[(size_t)row * RNK + tid] = f32_to_bf16(lb[(size_t)tid * OUT_F + row]);
}

// ------------- Kernel B: x f32 -> bf16 conversion fused with t = bf16(2*(x @ lora_a)) -------------
__global__ __launch_bounds__(256) void conv_lora_kernel(const float* __restrict__ x,
                                                        const float* __restrict__ la,
                                                        unsigned short* __restrict__ xbf,
                                                        unsigned short* __restrict__ tbf) {
    const int tid = threadIdx.x;
    const int lane = tid & 63;
    const int wid = tid >> 6;
    const int tok0 = blockIdx.x * 16 + wid * 4;
    float acc[4][16];
#pragma unroll
    for (int ti = 0; ti < 4; ++ti)
#pragma unroll
        for (int r = 0; r < 16; ++r) acc[ti][r] = 0.f;

    for (int j = 0; j < 32; ++j) {
        const int k = j * 128 + lane * 2;
        const float* lap = la + (size_t)k * RNK;
        f32x4 A[4], B[4];
#pragma unroll
        for (int h = 0; h < 4; ++h) A[h] = *(const f32x4*)(lap + h * 4);
#pragma unroll
        for (int h = 0; h < 4; ++h) B[h] = *(const f32x4*)(lap + RNK + h * 4);
#pragma unroll
        for (int ti = 0; ti < 4; ++ti) {
            const int t = tok0 + ti;
            f32x2 xv = *(const f32x2*)(x + (size_t)t * IN_F + k);
            const float xa = xv[0], xb = xv[1];
            uint32_t pack = (uint32_t)f32_to_bf16(xa) | ((uint32_t)f32_to_bf16(xb) << 16);
            *(uint32_t*)(xbf + (size_t)t * IN_F + k) = pack;
#pragma unroll
            for (int h = 0; h < 4; ++h)
#pragma unroll
                for (int e = 0; e < 4; ++e)
                    acc[ti][h * 4 + e] += xa * A[h][e] + xb * B[h][e];
        }
    }
#pragma unroll
    for (int ti = 0; ti < 4; ++ti)
#pragma unroll
        for (int r = 0; r < 16; ++r) {
            float s = acc[ti][r];
#pragma unroll
            for (int off = 1; off < 64; off <<= 1)
                s += __shfl_xor(s, off, 64);
            acc[ti][r] = s;
        }
    if (lane == 0) {
#pragma unroll
        for (int ti = 0; ti < 4; ++ti)
#pragma unroll
            for (int r = 0; r < 16; ++r)
                tbf[(size_t)(tok0 + ti) * RNK + r] = f32_to_bf16(2.0f * acc[ti][r]);
    }
}

// ------------- Kernel C: faithful m201 8-phase 256x256 bf16 MFMA GEMM + MFMA LoRA epilogue -------------
// 512 thr = 8 waves (2M x 4N). 2 K-tiles per iteration (slot0=even tile, slot1=odd tile).
// Per phase: {ds_read subtile | 1 half-tile stage (2 gloads)} -> s_barrier -> lgkmcnt(0) ->
// setprio(1) 16 MFMA setprio(0) -> s_barrier. vmcnt(4) only at phases 4 & 8.
__global__ __launch_bounds__(512, 2) void gemm8p_kernel(const unsigned short* __restrict__ xbf,
                                                        const unsigned short* __restrict__ wbf,
                                                        const unsigned short* __restrict__ tbf,
                                                        const unsigned short* __restrict__ lbt,
                                                        float* __restrict__ out) {
    __shared__ char lds[131072];  // A-slot0 | A-slot1 | B-slot0 | B-slot1, 32KB each

    const int bid = blockIdx.x;
    const int swz = (bid & 7) * 128 + (bid >> 3);  // bijective XCD swizzle (1024 % 8 == 0)
    const int tm = swz & 63, tn = swz >> 6;
    const int brow = tm * BM, bcol = tn * BN;

    const int tid = threadIdx.x;
    const int lane = tid & 63;
    const int wid = tid >> 6;
    const int wm = wid >> 2, wn = wid & 3;
    const int lrow = lane & 15;
    const int lko = lane >> 4;

    // ---- staging source (pre-swizzled global col so linear LDS dest == swizzled store) ----
    const int s_r = tid >> 3;                                    // 0..63
    const int scb = ((tid & 7) * 16) ^ (((tid >> 3) & 7) << 4);  // swizzled col-byte
    const unsigned short* gA = xbf + (size_t)(brow + s_r) * IN_F + (scb >> 1);
    const unsigned short* gB = wbf + (size_t)(bcol + s_r) * IN_F + (scb >> 1);

    char* const sA0 = (char*)lds;
    char* const sA1 = (char*)lds + 32768;
    char* const sB0 = (char*)lds + 65536;
    char* const sB1 = (char*)lds + 98304;

    // ---- fragment ds_read addressing (swizzled; R2 pattern, verified 0-conflict) ----
    const int aBase = (wm * 128 + lrow) * 128;
    const int bBase = (wn * 64 + lrow) * 128;
    const int koff[2] = {(lko * 16) ^ ((lrow & 7) << 4),
                         ((lko * 16) | 64) ^ ((lrow & 7) << 4)};

    f32x4 acc[8][4];
#pragma unroll
    for (int mf = 0; mf < 8; ++mf)
#pragma unroll
        for (int nf = 0; nf < 4; ++nf)
#pragma unroll
            for (int q = 0; q < 4; ++q) acc[mf][nf][q] = 0.f;

// half-tile stage: 128 rows x 64 k, 2 gloads (rows half*128+0..63, +64..127), linear dest tid*16
#define STAGE_A(kk, base, half)                                                                  \
    do {                                                                                         \
        direct_load16(gA + (size_t)((half) * 128) * IN_F + (kk), (base) + (half) * 16384 + tid * 16); \
        direct_load16(gA + (size_t)((half) * 128 + 64) * IN_F + (kk), (base) + (half) * 16384 + 8192 + tid * 16); \
    } while (0)
#define STAGE_B(kk, base, half)                                                                  \
    do {                                                                                         \
        direct_load16(gB + (size_t)((half) * 128) * IN_F + (kk), (base) + (half) * 16384 + tid * 16); \
        direct_load16(gB + (size_t)((half) * 128 + 64) * IN_F + (kk), (base) + (half) * 16384 + 8192 + tid * 16); \
    } while (0)

#define READ_AL(Ab)                                                         \
    _Pragma("unroll") for (int mf = 0; mf < 4; ++mf) {                      \
        aL[mf][0] = *(const s16x8*)((Ab) + aBase + mf * 2048 + koff[0]);    \
        aL[mf][1] = *(const s16x8*)((Ab) + aBase + mf * 2048 + koff[1]);    \
    }
#define READ_AH(Ab)                                                              \
    _Pragma("unroll") for (int mf = 0; mf < 4; ++mf) {                           \
        aH[mf][0] = *(const s16x8*)((Ab) + aBase + (4 + mf) * 2048 + koff[0]);   \
        aH[mf][1] = *(const s16x8*)((Ab) + aBase + (4 + mf) * 2048 + koff[1]);   \
    }
#define READ_BL(Bb)                                                         \
    _Pragma("unroll") for (int nf = 0; nf < 2; ++nf) {                      \
        bL[nf][0] = *(const s16x8*)((Bb) + bBase + nf * 2048 + koff[0]);    \
        bL[nf][1] = *(const s16x8*)((Bb) + bBase + nf * 2048 + koff[1]);    \
    }
#define READ_BH(Bb)                                                              \
    _Pragma("unroll") for (int nf = 0; nf < 2; ++nf) {                           \
        bH[nf][0] = *(const s16x8*)((Bb) + bBase + (2 + nf) * 2048 + koff[0]);   \
        bH[nf][1] = *(const s16x8*)((Bb) + bBase + (2 + nf) * 2048 + koff[1]);   \
    }
#define QUAD(MB, NB, AF, BF)                                                  \
    do {                                                                      \
        __builtin_amdgcn_s_setprio(1);                                        \
        _Pragma("unroll") for (int mf = 0; mf < 4; ++mf)                      \
            _Pragma("unroll") for (int nf = 0; nf < 2; ++nf) {                \
            acc[(MB) + mf][(NB) + nf] =                                       \
                mfma16(AF[mf][0], BF[nf][0], acc[(MB) + mf][(NB) + nf]);      \
            acc[(MB) + mf][(NB) + nf] =                                       \
                mfma16(AF[mf][1], BF[nf][1], acc[(MB) + mf][(NB) + nf]);      \
        }                                                                     \
        __builtin_amdgcn_s_setprio(0);                                        \
    } while (0)

    // ---- prologue: tile0 (4 halves) + tile1's B (2 halves); force tile0 landed ----
    STAGE_A(0, sA0, 0);
    STAGE_A(0, sA0, 1);
    STAGE_B(0, sB0, 0);
    STAGE_B(0, sB0, 1);
    STAGE_B(BK, sB1, 0);
    STAGE_B(BK, sB1, 1);
    VM(4);  // 12 issued, oldest 8 (tile0) landed; tile1-B in flight
    BAR();

    s16x8 aL[4][2], aH[4][2], bL[2][2], bH[2][2];

    for (int i = 0; i < NT / 2; ++i) {
        const int t = 2 * i;
        const int kk1 = (t + 1) * BK, kk2 = (t + 2) * BK, kk3 = (t + 3) * BK;
        const bool pf = (t + 2 < NT);  // == (t+3 < NT) for even t, NT even

        // ===== ph1: read aL,bL(t)@slot0 | stage A-half0(t+1)->slot1 | Q00(t) =====
        READ_AL(sA0);
        READ_BL(sB0);
        STAGE_A(kk1, sA1, 0);
        LGKM8();
        BAR();
        LGKM0();
        QUAD(0, 0, aL, bL);
        BAR();

        // ===== ph2: read bH(t) | stage A-half1(t+1)->slot1 | Q01(t) =====
        READ_BH(sB0);
        STAGE_A(kk1, sA1, 1);
        BAR();
        LGKM0();
        QUAD(0, 2, aL, bH);
        BAR();

        // ===== ph3: read aH(t) | stage B-half0(t+2)->slot0 | Q11(t) =====
        READ_AH(sA0);
        if (pf) STAGE_B(kk2, sB0, 0);
        BAR();
        LGKM0();
        QUAD(4, 2, aH, bH);
        BAR();

        // ===== ph4: stage B-half1(t+2)->slot0 | vmcnt gate | Q10(t) =====
        if (pf) {
            STAGE_B(kk2, sB0, 1);
            VM(4);  // forces A(t+1) (ph1,2) + B(t+1) (prologue/prev ph7,8) landed
        } else {
            VM(0);  // final iteration: force A(t+1) landed
        }
        BAR();
        QUAD(4, 0, aH, bL);
        BAR();

        // ===== ph5: read aL,bL(t+1)@slot1 | stage A-half0(t+2)->slot0 | Q00(t+1) =====
        READ_AL(sA1);
        READ_BL(sB1);
        if (pf) STAGE_A(kk2, sA0, 0);
        LGKM8();
        BAR();
        LGKM0();
        QUAD(0, 0, aL, bL);
        BAR();

        // ===== ph6: read bH(t+1) | stage A-half1(t+2)->slot0 | Q01(t+1) =====
        READ_BH(sB1);
        if (pf) STAGE_A(kk2, sA0, 1);
        BAR();
        LGKM0();
        QUAD(0, 2, aL, bH);
        BAR();

        // ===== ph7: read aH(t+1) | stage B-half0(t+3)->slot1 | Q11(t+1) =====
        READ_AH(sA1);
        if (pf) STAGE_B(kk3, sB1, 0);
        BAR();
        LGKM0();
        QUAD(4, 2, aH, bH);
        BAR();

        // ===== ph8: stage B-half1(t+3)->slot1 | vmcnt gate | Q10(t+1) =====
        if (pf) STAGE_B(kk3, sB1, 1);
        VM(4);  // forces tile t+2 (ph3,4,5,6) landed for next ph1; trivial on final iter
        BAR();
        QUAD(4, 0, aH, bL);
        BAR();
    }
#undef STAGE_A
#undef STAGE_B
#undef READ_AL
#undef READ_AH
#undef READ_BL
#undef READ_BH
#undef QUAD

    // ---- LoRA epilogue via MFMA: acc += t_tile(256x16) @ lbt_tile(256x16)^T (K=32, k>=16 zero) ----
    __syncthreads();
    unsigned short* tls = (unsigned short*)lds;           // [256][16]
    unsigned short* lls = (unsigned short*)(lds + 8192);  // [256][16]
    {
        const int row = tid >> 1, h = tid & 1;
        *(s16x8*)(tls + row * 16 + h * 8) = *(const s16x8*)(tbf + (size_t)(brow + row) * RNK + h * 8);
        *(s16x8*)(lls + row * 16 + h * 8) = *(const s16x8*)(lbt + (size_t)(bcol + row) * RNK + h * 8);
    }
    __syncthreads();
    {
        s16x8 z;
#pragma unroll
        for (int e = 0; e < 8; ++e) z[e] = 0;
        s16x8 at8[8], bl8[4];
#pragma unroll
        for (int mf = 0; mf < 8; ++mf) {
            const int row = wm * 128 + mf * 16 + lrow;
            at8[mf] = (lko < 2) ? *(const s16x8*)(tls + row * 16 + lko * 8) : z;
        }
#pragma unroll
        for (int nf = 0; nf < 4; ++nf) {
            const int row = wn * 64 + nf * 16 + lrow;
            bl8[nf] = (lko < 2) ? *(const s16x8*)(lls + row * 16 + lko * 8) : z;
        }
#pragma unroll
        for (int mf = 0; mf < 8; ++mf)
#pragma unroll
            for (int nf = 0; nf < 4; ++nf)
                acc[mf][nf] = mfma16(at8[mf], bl8[nf], acc[mf][nf]);
    }

    // ---- store: C/D layout col=lane&15, row=(lane>>4)*4+q (verified) ----
    const int c0 = bcol + wn * 64 + lrow;
    const int r0base = brow + wm * 128 + lko * 4;
#pragma unroll
    for (int mf = 0; mf < 8; ++mf)
#pragma unroll
        for (int q = 0; q < 4; ++q) {
            float* orow = out + (size_t)(r0base + mf * 16 + q) * OUT_F;
#pragma unroll
            for (int nf = 0; nf < 4; ++nf)
                orow[c0 + nf * 16] = acc[mf][nf][q];
        }
}

extern "C" void kernel_launch(void* const* d_in, const int* in_sizes, int n_in,
                              void* d_out, int out_size, void* d_ws, size_t ws_size,
                              hipStream_t stream) {
    const float* x  = (const float*)d_in[0];
    const float* w  = (const float*)d_in[1];
    const float* la = (const float*)d_in[2];
    const float* lb = (const float*)d_in[3];
    float* out = (float*)d_out;

    char* ws = (char*)d_ws;
    unsigned short* xbf = (unsigned short*)ws;                                    // 128 MiB
    unsigned short* wbf = (unsigned short*)(ws + (size_t)TOKENS * IN_F * 2);      // 32 MiB
    unsigned short* tbf = (unsigned short*)(ws + (size_t)TOKENS * IN_F * 2 + (size_t)OUT_F * IN_F * 2);           // 512 KiB
    unsigned short* lbt = (unsigned short*)(ws + (size_t)TOKENS * IN_F * 2 + (size_t)OUT_F * IN_F * 2
                                               + (size_t)TOKENS * RNK * 2);       // 128 KiB

    qd_weight_kernel<<<OUT_F, 256, 0, stream>>>(w, lb, wbf, lbt);
    conv_lora_kernel<<<TOKENS / 16, 256, 0, stream>>>(x, la, xbf, tbf);
    gemm8p_kernel<<<(TOKENS / BM) * (OUT_F / BN), 512, 0, stream>>>(xbf, wbf, tbf, lbt, out);
}

// Round 7
// 562.911 us; speedup vs baseline: 1.4041x; 1.2637x over previous
//
#include <hip/hip_runtime.h>
#include <stdint.h>

typedef __attribute__((ext_vector_type(4))) float f32x4;
typedef __attribute__((ext_vector_type(2))) float f32x2;
typedef __attribute__((ext_vector_type(8))) short s16x8;
typedef __attribute__((ext_vector_type(4))) int i32x4;

#define TOKENS 16384
#define IN_F 4096
#define OUT_F 4096
#define RNK 16
#define BM 256
#define BN 256
#define BKB 128               // K-tile in BYTES per row (=128 int8)
#define NTILE (IN_F / BKB)    // 32 K-tiles

static __device__ __forceinline__ unsigned short f32_to_bf16(float f) {
    uint32_t u = __builtin_bit_cast(uint32_t, f);
    uint32_t r = (u + 0x7FFFu + ((u >> 16) & 1u)) >> 16;
    return (unsigned short)r;
}

static __device__ __forceinline__ void direct_load16(const void* g, void* l) {
    __builtin_amdgcn_global_load_lds(
        (const __attribute__((address_space(1))) void*)(uintptr_t)g,
        (__attribute__((address_space(3))) void*)(uintptr_t)l,
        16, 0, 0);
}

static __device__ __forceinline__ i32x4 mfma_i8(i32x4 a, i32x4 b, i32x4 c) {
    return __builtin_amdgcn_mfma_i32_16x16x64_i8(a, b, c, 0, 0, 0);
}
static __device__ __forceinline__ f32x4 mfma16(s16x8 a, s16x8 b, f32x4 c) {
    return __builtin_amdgcn_mfma_f32_16x16x32_bf16(a, b, c, 0, 0, 0);
}

#define BAR() asm volatile("s_barrier" ::: "memory")
#define VM(n) asm volatile("s_waitcnt vmcnt(" #n ")" ::: "memory")
#define LGKM0()                                                  \
    do {                                                         \
        asm volatile("s_waitcnt lgkmcnt(0)" ::: "memory");       \
        __builtin_amdgcn_sched_barrier(0);                       \
    } while (0)
#define LGKM8() asm volatile("s_waitcnt lgkmcnt(8)" ::: "memory")

// ---------------- Kernel A: per-row absmax int8 quant of W -> wq int8 + wscale, + lora_b transpose ----------------
__global__ __launch_bounds__(256) void qd_weight_kernel(const float* __restrict__ w,
                                                        const float* __restrict__ lb,
                                                        uint32_t* __restrict__ wq,      // [4096][4096] int8 as u32 words
                                                        float* __restrict__ wscale,
                                                        unsigned short* __restrict__ lbt) {
    const int row = blockIdx.x;
    const int tid = threadIdx.x;
    const float* wr = w + (size_t)row * IN_F;
    f32x4 v[4];
#pragma unroll
    for (int p = 0; p < 4; ++p)
        v[p] = *(const f32x4*)(wr + (size_t)(tid + p * 256) * 4);
    float m = 0.f;
#pragma unroll
    for (int p = 0; p < 4; ++p)
#pragma unroll
        for (int e = 0; e < 4; ++e)
            m = fmaxf(m, fabsf(v[p][e]));
#pragma unroll
    for (int off = 1; off < 64; off <<= 1)
        m = fmaxf(m, __shfl_xor(m, off, 64));
    __shared__ float red[4];
    if ((tid & 63) == 0) red[tid >> 6] = m;
    __syncthreads();
    m = fmaxf(fmaxf(red[0], red[1]), fmaxf(red[2], red[3]));
    const float scale = m * (1.0f / 127.0f);
    const float denom = scale + 1e-8f;
#pragma unroll
    for (int p = 0; p < 4; ++p) {
        uint32_t pack = 0;
#pragma unroll
        for (int e = 0; e < 4; ++e) {
            float q = rintf(v[p][e] / denom);  // RNE, matches jnp.round
            q = fminf(fmaxf(q, -128.f), 127.f);
            pack |= ((uint32_t)(uint8_t)(int)q) << (8 * e);
        }
        wq[(size_t)row * (IN_F / 4) + tid + p * 256] = pack;
    }
    if (tid == 0) wscale[row] = scale;
    if (tid < RNK)
        lbt[(size_t)row * RNK + tid] = f32_to_bf16(lb[(size_t)tid * OUT_F + row]);
}

// ---------------- Kernel A2: per-token absmax of x -> xscale (amax/127), xinv (127/amax) ----------------
__global__ __launch_bounds__(256) void xabsmax_kernel(const float* __restrict__ x,
                                                      float* __restrict__ xscale,
                                                      float* __restrict__ xinv) {
    const int lane = threadIdx.x & 63;
    const int row = blockIdx.x * 4 + (threadIdx.x >> 6);
    const float* xr = x + (size_t)row * IN_F;
    float m = 0.f;
#pragma unroll
    for (int j = 0; j < 16; ++j) {
        f32x4 v = *(const f32x4*)(xr + j * 256 + lane * 4);
#pragma unroll
        for (int e = 0; e < 4; ++e) m = fmaxf(m, fabsf(v[e]));
    }
#pragma unroll
    for (int off = 1; off < 64; off <<= 1)
        m = fmaxf(m, __shfl_xor(m, off, 64));
    if (lane == 0) {
        m = fmaxf(m, 1e-6f);
        xscale[row] = m * (1.0f / 127.0f);
        xinv[row] = 127.0f / m;
    }
}

// ------------- Kernel B: x f32 -> int8 quantize fused with t = bf16(2*(x @ lora_a)) -------------
__global__ __launch_bounds__(256) void conv_lora_kernel(const float* __restrict__ x,
                                                        const float* __restrict__ la,
                                                        const float* __restrict__ xinv,
                                                        unsigned short* __restrict__ xq,  // int8 pairs
                                                        unsigned short* __restrict__ tbf) {
    const int tid = threadIdx.x;
    const int lane = tid & 63;
    const int wid = tid >> 6;
    const int tok0 = blockIdx.x * 16 + wid * 4;
    float inv[4];
#pragma unroll
    for (int ti = 0; ti < 4; ++ti) inv[ti] = xinv[tok0 + ti];
    float acc[4][16];
#pragma unroll
    for (int ti = 0; ti < 4; ++ti)
#pragma unroll
        for (int r = 0; r < 16; ++r) acc[ti][r] = 0.f;

    for (int j = 0; j < 32; ++j) {
        const int k = j * 128 + lane * 2;
        const float* lap = la + (size_t)k * RNK;
        f32x4 A[4], B[4];
#pragma unroll
        for (int h = 0; h < 4; ++h) A[h] = *(const f32x4*)(lap + h * 4);
#pragma unroll
        for (int h = 0; h < 4; ++h) B[h] = *(const f32x4*)(lap + RNK + h * 4);
#pragma unroll
        for (int ti = 0; ti < 4; ++ti) {
            const int t = tok0 + ti;
            f32x2 xv = *(const f32x2*)(x + (size_t)t * IN_F + k);
            const float xa = xv[0], xb = xv[1];
            float qa = fminf(fmaxf(rintf(xa * inv[ti]), -128.f), 127.f);
            float qb = fminf(fmaxf(rintf(xb * inv[ti]), -128.f), 127.f);
            unsigned short pack =
                (unsigned short)((uint8_t)(int)qa | (((uint32_t)(uint8_t)(int)qb) << 8));
            xq[((size_t)t * IN_F + k) >> 1] = pack;
#pragma unroll
            for (int h = 0; h < 4; ++h)
#pragma unroll
                for (int e = 0; e < 4; ++e)
                    acc[ti][h * 4 + e] += xa * A[h][e] + xb * B[h][e];
        }
    }
#pragma unroll
    for (int ti = 0; ti < 4; ++ti)
#pragma unroll
        for (int r = 0; r < 16; ++r) {
            float s = acc[ti][r];
#pragma unroll
            for (int off = 1; off < 64; off <<= 1)
                s += __shfl_xor(s, off, 64);
            acc[ti][r] = s;
        }
    if (lane == 0) {
#pragma unroll
        for (int ti = 0; ti < 4; ++ti)
#pragma unroll
            for (int r = 0; r < 16; ++r)
                tbf[(size_t)(tok0 + ti) * RNK + r] = f32_to_bf16(2.0f * acc[ti][r]);
    }
}

// ------------- Kernel C: 8-phase 256x256 i8 MFMA GEMM (S = xq @ wq^T, exact i32) -------------
// Byte-identical geometry to the bf16 BK=64 kernel: 128-byte K-rows, same swizzle/staging/ledger.
// Epilogue: out = xscale[row]*wscale[col]*S + lora (bf16 MFMA, rank-16).
__global__ __launch_bounds__(512, 2) void gemm8p_i8_kernel(const char* __restrict__ xq,
                                                           const char* __restrict__ wq,
                                                           const float* __restrict__ xscale,
                                                           const float* __restrict__ wscale,
                                                           const unsigned short* __restrict__ tbf,
                                                           const unsigned short* __restrict__ lbt,
                                                           float* __restrict__ out) {
    __shared__ char lds[131072];  // A-slot0 | A-slot1 | B-slot0 | B-slot1, 32KB each

    const int bid = blockIdx.x;
    const int swz = (bid & 7) * 128 + (bid >> 3);  // bijective XCD swizzle (1024 % 8 == 0)
    const int tm = swz & 63, tn = swz >> 6;
    const int brow = tm * BM, bcol = tn * BN;

    const int tid = threadIdx.x;
    const int lane = tid & 63;
    const int wid = tid >> 6;
    const int wm = wid >> 2, wn = wid & 3;
    const int lrow = lane & 15;
    const int lko = lane >> 4;

    // ---- staging source (pre-swizzled global byte-col so linear LDS dest == swizzled store) ----
    const int s_r = tid >> 3;                                    // 0..63
    const int scb = ((tid & 7) * 16) ^ (((tid >> 3) & 7) << 4);  // swizzled col-byte 0..127
    const char* gA = xq + (size_t)(brow + s_r) * IN_F + scb;
    const char* gB = wq + (size_t)(bcol + s_r) * IN_F + scb;

    char* const sA0 = (char*)lds;
    char* const sA1 = (char*)lds + 32768;
    char* const sB0 = (char*)lds + 65536;
    char* const sB1 = (char*)lds + 98304;

    // ---- fragment ds_read addressing (same proven 0-conflict byte pattern) ----
    const int aBase = (wm * 128 + lrow) * 128;
    const int bBase = (wn * 64 + lrow) * 128;
    const int koff[2] = {(lko * 16) ^ ((lrow & 7) << 4),
                         ((lko * 16) | 64) ^ ((lrow & 7) << 4)};

    i32x4 acc[8][4];
#pragma unroll
    for (int mf = 0; mf < 8; ++mf)
#pragma unroll
        for (int nf = 0; nf < 4; ++nf)
#pragma unroll
            for (int q = 0; q < 4; ++q) acc[mf][nf][q] = 0;

#define STAGE_A(kk, base, half)                                                                       \
    do {                                                                                              \
        direct_load16(gA + (size_t)((half) * 128) * IN_F + (kk), (base) + (half) * 16384 + tid * 16); \
        direct_load16(gA + (size_t)((half) * 128 + 64) * IN_F + (kk),                                 \
                      (base) + (half) * 16384 + 8192 + tid * 16);                                     \
    } while (0)
#define STAGE_B(kk, base, half)                                                                       \
    do {                                                                                              \
        direct_load16(gB + (size_t)((half) * 128) * IN_F + (kk), (base) + (half) * 16384 + tid * 16); \
        direct_load16(gB + (size_t)((half) * 128 + 64) * IN_F + (kk),                                 \
                      (base) + (half) * 16384 + 8192 + tid * 16);                                     \
    } while (0)

#define READ_AL(Ab)                                                          \
    _Pragma("unroll") for (int mf = 0; mf < 4; ++mf) {                       \
        aL[mf][0] = *(const i32x4*)((Ab) + aBase + mf * 2048 + koff[0]);     \
        aL[mf][1] = *(const i32x4*)((Ab) + aBase + mf * 2048 + koff[1]);     \
    }
#define READ_AH(Ab)                                                               \
    _Pragma("unroll") for (int mf = 0; mf < 4; ++mf) {                            \
        aH[mf][0] = *(const i32x4*)((Ab) + aBase + (4 + mf) * 2048 + koff[0]);    \
        aH[mf][1] = *(const i32x4*)((Ab) + aBase + (4 + mf) * 2048 + koff[1]);    \
    }
#define READ_BL(Bb)                                                          \
    _Pragma("unroll") for (int nf = 0; nf < 2; ++nf) {                       \
        bL[nf][0] = *(const i32x4*)((Bb) + bBase + nf * 2048 + koff[0]);     \
        bL[nf][1] = *(const i32x4*)((Bb) + bBase + nf * 2048 + koff[1]);     \
    }
#define READ_BH(Bb)                                                               \
    _Pragma("unroll") for (int nf = 0; nf < 2; ++nf) {                            \
        bH[nf][0] = *(const i32x4*)((Bb) + bBase + (2 + nf) * 2048 + koff[0]);    \
        bH[nf][1] = *(const i32x4*)((Bb) + bBase + (2 + nf) * 2048 + koff[1]);    \
    }
#define QUAD(MB, NB, AF, BF)                                                  \
    do {                                                                      \
        __builtin_amdgcn_s_setprio(1);                                        \
        _Pragma("unroll") for (int mf = 0; mf < 4; ++mf)                      \
            _Pragma("unroll") for (int nf = 0; nf < 2; ++nf) {                \
            acc[(MB) + mf][(NB) + nf] =                                       \
                mfma_i8(AF[mf][0], BF[nf][0], acc[(MB) + mf][(NB) + nf]);     \
            acc[(MB) + mf][(NB) + nf] =                                       \
                mfma_i8(AF[mf][1], BF[nf][1], acc[(MB) + mf][(NB) + nf]);     \
        }                                                                     \
        __builtin_amdgcn_s_setprio(0);                                        \
    } while (0)

    // ---- prologue: tile0 (4 halves) + tile1's B (2 halves); force tile0 landed ----
    STAGE_A(0, sA0, 0);
    STAGE_A(0, sA0, 1);
    STAGE_B(0, sB0, 0);
    STAGE_B(0, sB0, 1);
    STAGE_B(BKB, sB1, 0);
    STAGE_B(BKB, sB1, 1);
    VM(4);
    BAR();

    i32x4 aL[4][2], aH[4][2], bL[2][2], bH[2][2];

    for (int i = 0; i < NTILE / 2; ++i) {
        const int t = 2 * i;
        const int kk1 = (t + 1) * BKB, kk2 = (t + 2) * BKB, kk3 = (t + 3) * BKB;
        const bool pf = (t + 2 < NTILE);

        // ===== ph1 =====
        READ_AL(sA0);
        READ_BL(sB0);
        STAGE_A(kk1, sA1, 0);
        LGKM8();
        BAR();
        LGKM0();
        QUAD(0, 0, aL, bL);
        BAR();

        // ===== ph2 =====
        READ_BH(sB0);
        STAGE_A(kk1, sA1, 1);
        BAR();
        LGKM0();
        QUAD(0, 2, aL, bH);
        BAR();

        // ===== ph3 =====
        READ_AH(sA0);
        if (pf) STAGE_B(kk2, sB0, 0);
        BAR();
        LGKM0();
        QUAD(4, 2, aH, bH);
        BAR();

        // ===== ph4 =====
        if (pf) {
            STAGE_B(kk2, sB0, 1);
            VM(4);
        } else {
            VM(0);
        }
        BAR();
        QUAD(4, 0, aH, bL);
        BAR();

        // ===== ph5 =====
        READ_AL(sA1);
        READ_BL(sB1);
        if (pf) STAGE_A(kk2, sA0, 0);
        LGKM8();
        BAR();
        LGKM0();
        QUAD(0, 0, aL, bL);
        BAR();

        // ===== ph6 =====
        READ_BH(sB1);
        if (pf) STAGE_A(kk2, sA0, 1);
        BAR();
        LGKM0();
        QUAD(0, 2, aL, bH);
        BAR();

        // ===== ph7 =====
        READ_AH(sA1);
        if (pf) STAGE_B(kk3, sB1, 0);
        BAR();
        LGKM0();
        QUAD(4, 2, aH, bH);
        BAR();

        // ===== ph8 =====
        if (pf) STAGE_B(kk3, sB1, 1);
        VM(4);
        BAR();
        QUAD(4, 0, aH, bL);
        BAR();
    }
#undef STAGE_A
#undef STAGE_B
#undef READ_AL
#undef READ_AH
#undef READ_BL
#undef READ_BH
#undef QUAD

    // ---- epilogue: lora tiles to LDS (bf16), scales, combine ----
    __syncthreads();
    unsigned short* tls = (unsigned short*)lds;           // [256][16] bf16 t (prescaled by 2)
    unsigned short* lls = (unsigned short*)(lds + 8192);  // [256][16] bf16 lbt
    {
        const int row = tid >> 1, h = tid & 1;
        *(s16x8*)(tls + row * 16 + h * 8) = *(const s16x8*)(tbf + (size_t)(brow + row) * RNK + h * 8);
        *(s16x8*)(lls + row * 16 + h * 8) = *(const s16x8*)(lbt + (size_t)(bcol + row) * RNK + h * 8);
    }
    __syncthreads();

    const int c0 = bcol + wn * 64 + lrow;
    const int r0base = brow + wm * 128 + lko * 4;

    s16x8 z;
#pragma unroll
    for (int e = 0; e < 8; ++e) z[e] = 0;
    s16x8 at8[8], bl8[4];
#pragma unroll
    for (int mf = 0; mf < 8; ++mf) {
        const int row = wm * 128 + mf * 16 + lrow;
        at8[mf] = (lko < 2) ? *(const s16x8*)(tls + row * 16 + lko * 8) : z;
    }
#pragma unroll
    for (int nf = 0; nf < 4; ++nf) {
        const int row = wn * 64 + nf * 16 + lrow;
        bl8[nf] = (lko < 2) ? *(const s16x8*)(lls + row * 16 + lko * 8) : z;
    }
    float ws4[4];
#pragma unroll
    for (int nf = 0; nf < 4; ++nf) ws4[nf] = wscale[c0 + nf * 16];

    const f32x4 zf = {0.f, 0.f, 0.f, 0.f};
#pragma unroll
    for (int mf = 0; mf < 8; ++mf) {
        f32x4 lor[4];
#pragma unroll
        for (int nf = 0; nf < 4; ++nf) lor[nf] = mfma16(at8[mf], bl8[nf], zf);
        const f32x4 xs4 = *(const f32x4*)(xscale + r0base + mf * 16);
#pragma unroll
        for (int q = 0; q < 4; ++q) {
            float* orow = out + (size_t)(r0base + mf * 16 + q) * OUT_F;
#pragma unroll
            for (int nf = 0; nf < 4; ++nf)
                orow[c0 + nf * 16] =
                    xs4[q] * ws4[nf] * (float)acc[mf][nf][q] + lor[nf][q];
        }
    }
}

extern "C" void kernel_launch(void* const* d_in, const int* in_sizes, int n_in,
                              void* d_out, int out_size, void* d_ws, size_t ws_size,
                              hipStream_t stream) {
    const float* x  = (const float*)d_in[0];
    const float* w  = (const float*)d_in[1];
    const float* la = (const float*)d_in[2];
    const float* lb = (const float*)d_in[3];
    float* out = (float*)d_out;

    char* ws = (char*)d_ws;
    size_t off = 0;
    char* xq = ws + off;                 off += (size_t)TOKENS * IN_F;      // 64 MiB
    char* wqb = ws + off;                off += (size_t)OUT_F * IN_F;       // 16 MiB
    unsigned short* tbf = (unsigned short*)(ws + off); off += (size_t)TOKENS * RNK * 2;  // 512 KiB
    unsigned short* lbt = (unsigned short*)(ws + off); off += (size_t)OUT_F * RNK * 2;   // 128 KiB
    float* xscale = (float*)(ws + off);  off += (size_t)TOKENS * 4;         // 64 KiB
    float* xinv = (float*)(ws + off);    off += (size_t)TOKENS * 4;         // 64 KiB
    float* wscale = (float*)(ws + off);  off += (size_t)OUT_F * 4;          // 16 KiB

    qd_weight_kernel<<<OUT_F, 256, 0, stream>>>(w, lb, (uint32_t*)wqb, wscale, lbt);
    xabsmax_kernel<<<TOKENS / 4, 256, 0, stream>>>(x, xscale, xinv);
    conv_lora_kernel<<<TOKENS / 16, 256, 0, stream>>>(x, la, xinv, (unsigned short*)xq, tbf);
    gemm8p_i8_kernel<<<(TOKENS / BM) * (OUT_F / BN), 512, 0, stream>>>(
        xq, wqb, xscale, wscale, tbf, lbt, out);
}